// Round 2
// baseline (1044.616 us; speedup 1.0000x reference)
//
#include <hip/hip_runtime.h>

// GQA attention forward. Inputs/outputs FP32 (per reference); internal compute
// bf16 MFMA (threshold is 2% of max|ref|). BS=4 SEQ=1024 DM=4096 HQ=32 HKV=8 DK=DV=128.
// Pipeline: cvt mask -> transpose+cvt weights -> Q/KV proj GEMMs (A: fp32->bf16
// fused staging, B: global_load_lds) -> RoPE -> flash attention -> O proj (fp32 out).

using ushort = unsigned short;
typedef __attribute__((ext_vector_type(8))) short short8;   // 8 bf16 (4 VGPRs)
typedef __attribute__((ext_vector_type(4))) short short4v;  // 4 bf16
typedef __attribute__((ext_vector_type(4))) float f32x4;    // MFMA C/D

__device__ __forceinline__ ushort f2bf(float x) {  // RNE fp32->bf16
  unsigned int u = __float_as_uint(x);
  u += 0x7FFFu + ((u >> 16) & 1u);
  return (ushort)(u >> 16);
}
__device__ __forceinline__ float bf2f(ushort h) {
  return __uint_as_float(((unsigned int)h) << 16);
}

__device__ __forceinline__ void async_copy16(const void* g, void* l) {
  // LDS dest = wave-uniform base + lane*16 (pass uniform l).
  __builtin_amdgcn_global_load_lds((const __attribute__((address_space(1))) void*)g,
                                   (__attribute__((address_space(3))) void*)l, 16, 0, 0);
}

// ---------------------------------------------------------------------------
// fp32 -> bf16 elementwise (mask), 4 elems/thread
// ---------------------------------------------------------------------------
__global__ __launch_bounds__(256)
void cvt_f32_bf16(const float* __restrict__ in, ushort* __restrict__ out, int n4) {
  const int i = blockIdx.x * 256 + threadIdx.x;
  if (i < n4) {
    const float4 f = ((const float4*)in)[i];
    short4v v;
    v[0] = (short)f2bf(f.x); v[1] = (short)f2bf(f.y);
    v[2] = (short)f2bf(f.z); v[3] = (short)f2bf(f.w);
    ((short4v*)out)[i] = v;
  }
}

// ---------------------------------------------------------------------------
// Weight transpose+convert: B fp32 [4096][N] -> Bt bf16 [N][4096]
// ---------------------------------------------------------------------------
__global__ __launch_bounds__(256)
void transpose_cvt(const float* __restrict__ B, ushort* __restrict__ Bt, int N) {
  __shared__ ushort t[64][72];  // +8 pad breaks bank conflicts
  const int n0 = blockIdx.x * 64, k0 = blockIdx.y * 64;
  const int tid = threadIdx.x;
  const int r = tid >> 3, c8 = (tid & 7) * 8;
#pragma unroll
  for (int p = 0; p < 2; p++) {
    const float* src = B + (size_t)(k0 + r + p * 32) * N + n0 + c8;
    const float4 f0 = *(const float4*)src;
    const float4 f1 = *(const float4*)(src + 4);
    ushort* d = &t[r + p * 32][c8];
    d[0] = f2bf(f0.x); d[1] = f2bf(f0.y); d[2] = f2bf(f0.z); d[3] = f2bf(f0.w);
    d[4] = f2bf(f1.x); d[5] = f2bf(f1.y); d[6] = f2bf(f1.z); d[7] = f2bf(f1.w);
  }
  __syncthreads();
#pragma unroll
  for (int p = 0; p < 2; p++) {
    const int n = r + p * 32;
    short8 o;
#pragma unroll
    for (int j = 0; j < 8; j++) o[j] = (short)t[c8 + j][n];
    *(short8*)(Bt + (size_t)(n0 + n) * 4096 + k0 + c8) = o;
  }
}

// ---------------------------------------------------------------------------
// GEMM C = A[4096x4096] * Bt[Nx4096]^T, bf16 MFMA, fp32 accum. K=4096.
// AF32: A is fp32, converted to bf16 during LDS staging (ds_write_b128);
// else A is bf16 and staged via global_load_lds. B always bf16 global_load_lds.
// MODE 0: C fp32 row-major [M][N] (final O-projection -> d_out)
// MODE 1: Q head-major bf16 [b][32][s][128] (scale folded)
// MODE 4: fused KV: n<1024 -> K bf16 [b][8][s][128]; n>=1024 -> V^T bf16 [b][8][128][s]
// ---------------------------------------------------------------------------
template <int MODE, bool AF32>
__global__ __launch_bounds__(256, 2)
void gemm_bt(const float* __restrict__ Af, const float* __restrict__ A2f,
             const ushort* __restrict__ Abf, const ushort* __restrict__ Bt,
             ushort* __restrict__ C, ushort* __restrict__ C2,
             float* __restrict__ Cf, int N, float scale) {
  constexpr int K = 4096;
  __shared__ alignas(16) ushort As[128 * 32];
  __shared__ alignas(16) ushort Bs[128 * 32];
  const int tid = threadIdx.x;
  const int wave = tid >> 6, lane = tid & 63;
  const int quad = lane >> 4, l16 = lane & 15;
  const int m0 = blockIdx.y * 128, n0 = blockIdx.x * 128;
  const int wm = (wave & 1) * 64, wn = (wave >> 1) * 64;

  const size_t aoff = (size_t)(m0 + wave * 16 + (lane >> 2)) * K + (lane & 3) * 8;
  const float* gAf = nullptr;
  const ushort* gAb = nullptr;
  if constexpr (AF32) {
    const float* Ause = Af;
    if constexpr (MODE == 4) {
      if (n0 >= 1024) Ause = A2f;  // V half reads `value`
    }
    gAf = Ause + aoff;
  } else {
    gAb = Abf + aoff;
  }
  const ushort* gB = Bt + (size_t)(n0 + wave * 16 + (lane >> 2)) * K + (lane & 3) * 8;
  ushort* lA = As + wave * 512;  // wave-uniform LDS bases
  ushort* lB = Bs + wave * 512;
  constexpr size_t rstep = (size_t)64 * K;

  f32x4 acc[4][4] = {};

  for (int kt = 0; kt < K; kt += 32) {
    if constexpr (AF32) {
      const float4 a0 = *(const float4*)(gAf + kt);
      const float4 a1 = *(const float4*)(gAf + kt + 4);
      const float4 b0 = *(const float4*)(gAf + rstep + kt);
      const float4 b1 = *(const float4*)(gAf + rstep + kt + 4);
      short8 v0, v1;
      v0[0] = (short)f2bf(a0.x); v0[1] = (short)f2bf(a0.y);
      v0[2] = (short)f2bf(a0.z); v0[3] = (short)f2bf(a0.w);
      v0[4] = (short)f2bf(a1.x); v0[5] = (short)f2bf(a1.y);
      v0[6] = (short)f2bf(a1.z); v0[7] = (short)f2bf(a1.w);
      v1[0] = (short)f2bf(b0.x); v1[1] = (short)f2bf(b0.y);
      v1[2] = (short)f2bf(b0.z); v1[3] = (short)f2bf(b0.w);
      v1[4] = (short)f2bf(b1.x); v1[5] = (short)f2bf(b1.y);
      v1[6] = (short)f2bf(b1.z); v1[7] = (short)f2bf(b1.w);
      *(short8*)(lA + lane * 8) = v0;
      *(short8*)(lA + 2048 + lane * 8) = v1;
    } else {
      async_copy16(gAb + kt, lA);
      async_copy16(gAb + rstep + kt, lA + 2048);
    }
    async_copy16(gB + kt, lB);
    async_copy16(gB + rstep + kt, lB + 2048);
    __syncthreads();
    short8 af[4], bfrag[4];
#pragma unroll
    for (int i = 0; i < 4; i++) {
      af[i] = *(const short8*)(As + (wm + i * 16 + l16) * 32 + quad * 8);
      bfrag[i] = *(const short8*)(Bs + (wn + i * 16 + l16) * 32 + quad * 8);
    }
#pragma unroll
    for (int i = 0; i < 4; i++)
#pragma unroll
      for (int j = 0; j < 4; j++)
        acc[i][j] = __builtin_amdgcn_mfma_f32_16x16x32_bf16(af[i], bfrag[j],
                                                            acc[i][j], 0, 0, 0);
    __syncthreads();
  }

#pragma unroll
  for (int i = 0; i < 4; i++) {
#pragma unroll
    for (int j = 0; j < 4; j++) {
      const int mb = m0 + wm + i * 16 + quad * 4;
      const int n = n0 + wn + j * 16 + l16;
#pragma unroll
      for (int r = 0; r < 4; r++) {
        const int m = mb + r;
        const float xv = acc[i][j][r] * scale;
        if constexpr (MODE == 0) {
          Cf[(size_t)m * N + n] = xv;
        } else if constexpr (MODE == 1) {
          const int b = m >> 10, s = m & 1023, hh = n >> 7, d = n & 127;
          C[(((size_t)b * 32 + hh) * 1024 + s) * 128 + d] = f2bf(xv);
        } else {  // MODE 4
          const int b = m >> 10, s = m & 1023;
          if (n < 1024) {
            const int hh = n >> 7, d = n & 127;
            C[(((size_t)b * 8 + hh) * 1024 + s) * 128 + d] = f2bf(xv);
          } else {
            const int n2 = n - 1024;
            const int hh = n2 >> 7, d = n2 & 127;
            C2[(((size_t)b * 8 + hh) * 128 + d) * 1024 + s] = f2bf(xv);
          }
        }
      }
    }
  }
}

// ---------------------------------------------------------------------------
// RoPE in place on head-major bf16 Q and K (rows of 128, s = row % 1024).
// ---------------------------------------------------------------------------
__global__ void rope_kernel(ushort* __restrict__ Q, ushort* __restrict__ Kh,
                            const int* __restrict__ posp, int nQrows) {
  const int row = blockIdx.x;
  const int d = threadIdx.x;  // 64
  ushort* p = (row < nQrows) ? (Q + (size_t)row * 128)
                             : (Kh + (size_t)(row - nQrows) * 128);
  const int s = row & 1023;
  const float pos = (float)(s + posp[0]);
  const float inv = exp2f((float)d * (-13.287712379549449f / 64.0f));  // 10000^(-d/64)
  const float ang = pos * inv;
  const float cs = cosf(ang), sn = sinf(ang);
  const float x1 = bf2f(p[d]);
  const float x2 = bf2f(p[d + 64]);
  p[d] = f2bf(x1 * cs - x2 * sn);
  p[d + 64] = f2bf(x2 * cs + x1 * sn);
}

// ---------------------------------------------------------------------------
// Flash attention. Block = 64 q-rows (4 waves x 16), 16 k-tiles of 64.
// XOR-swizzled 16B chunks for K/V/Q staging (conflict-free ds_read_b128).
// P (C-layout -> A-layout) round-trips through LDS ALIASED onto Ks (rows 0..35),
// legal because an extra mid-iteration barrier separates all Ks reads from P
// writes. Static LDS = 56 KB (<= 64 KB/workgroup limit).
// ---------------------------------------------------------------------------
__global__ __launch_bounds__(256, 2)
void attn_kernel(const ushort* __restrict__ Qh, const ushort* __restrict__ Kh,
                 const ushort* __restrict__ Vt, const ushort* __restrict__ Mk,
                 ushort* __restrict__ Oh) {
  __shared__ alignas(16) ushort Qs[64 * 128];
  __shared__ alignas(16) ushort Ks[64 * 128];
  __shared__ alignas(16) ushort Vs[128 * 64];  // [d][key]
  __shared__ alignas(16) ushort Ms[64 * 64];   // bf16 mask tile
  ushort* Ps = Ks;  // alias: P staging uses Ks[0..4607], guarded by mid-barrier
  const int b = blockIdx.z, h = blockIdx.y;
  const int q0 = blockIdx.x * 64;
  const int hkv = h >> 2;
  const int tid = threadIdx.x;
  const int wave = tid >> 6, lane = tid & 63;
  const int quad = lane >> 4, l16 = lane & 15;

  const ushort* Qg = Qh + (((size_t)b * 32 + h) * 1024 + q0) * 128;
  const ushort* Kg = Kh + ((size_t)b * 8 + hkv) * (size_t)(1024 * 128);
  const ushort* Vg = Vt + ((size_t)b * 8 + hkv) * (size_t)(128 * 1024);
  const ushort* Mg = Mk + ((size_t)b * 1024 + q0) * 1024;

  // stage Q once: chunk(row,kc) -> LDS pos kc ^ (row&15)
#pragma unroll
  for (int c = 0; c < 4; c++) {
    const int i = wave * 4 + c;
    const int row = i * 4 + (lane >> 4);
    const int kc = (lane & 15) ^ (c * 4 + (lane >> 4));
    async_copy16(Qg + (size_t)row * 128 + kc * 8, Qs + i * 512);
  }

  float m_i[4], l_i[4];
#pragma unroll
  for (int r = 0; r < 4; r++) { m_i[r] = -1e30f; l_i[r] = 0.0f; }
  f32x4 acc_o[8] = {};

  const int vr = lane >> 3;
  const int vkc = (lane & 7) ^ (vr & 7);

  for (int kt = 0; kt < 1024; kt += 64) {
#pragma unroll
    for (int c = 0; c < 4; c++) {  // K tile 64x128, swizzled as Q
      const int i = wave * 4 + c;
      const int row = i * 4 + (lane >> 4);
      const int kc = (lane & 15) ^ (c * 4 + (lane >> 4));
      async_copy16(Kg + (size_t)(kt + row) * 128 + kc * 8, Ks + i * 512);
    }
#pragma unroll
    for (int c = 0; c < 4; c++) {  // V^T tile 128x64, 8-chunk swizzle
      const int i = wave * 4 + c;
      async_copy16(Vg + (size_t)(i * 8 + vr) * 1024 + kt + vkc * 8, Vs + i * 512);
    }
#pragma unroll
    for (int c = 0; c < 2; c++)  // mask tile 64x64 bf16, linear
      async_copy16(Mg + (size_t)(wave * 8 + c * 32 + vr) * 1024 + kt + (lane & 7) * 8,
                   Ms + wave * 512 + c * 2048);
    __syncthreads();

    // S = Q K^T (Q pre-scaled by 1/sqrt(128))
    f32x4 s[4] = {};
    const int qrow = (wave * 16 + l16) * 128;
#pragma unroll
    for (int ks = 0; ks < 4; ks++) {
      const int ko = ((ks * 4 + quad) ^ l16) * 8;
      const short8 aq = *(const short8*)(Qs + qrow + ko);
#pragma unroll
      for (int nt = 0; nt < 4; nt++) {
        const short8 bk = *(const short8*)(Ks + (nt * 16 + l16) * 128 + ko);
        s[nt] = __builtin_amdgcn_mfma_f32_16x16x32_bf16(aq, bk, s[nt], 0, 0, 0);
      }
    }
    __syncthreads();  // all Ks reads done device-wide before P overwrites Ks region

    // additive mask (C/D layout: row = quad*4+reg, col = lane&15)
#pragma unroll
    for (int nt = 0; nt < 4; nt++)
#pragma unroll
      for (int r = 0; r < 4; r++)
        s[nt][r] += bf2f(Ms[(wave * 16 + quad * 4 + r) * 64 + nt * 16 + l16]);

    // online softmax: quad's 16 lanes hold one row's 16 columns
    float al[4];
#pragma unroll
    for (int r = 0; r < 4; r++) {
      float mx = fmaxf(fmaxf(s[0][r], s[1][r]), fmaxf(s[2][r], s[3][r]));
#pragma unroll
      for (int off = 1; off < 16; off <<= 1) mx = fmaxf(mx, __shfl_xor(mx, off));
      const float mnew = fmaxf(m_i[r], mx);
      al[r] = __expf(m_i[r] - mnew);
      float sum = 0.0f;
#pragma unroll
      for (int nt = 0; nt < 4; nt++) {
        const float pv = __expf(s[nt][r] - mnew);
        s[nt][r] = pv;
        sum += pv;
      }
#pragma unroll
      for (int off = 1; off < 16; off <<= 1) sum += __shfl_xor(sum, off);
      l_i[r] = l_i[r] * al[r] + sum;
      m_i[r] = mnew;
    }
#pragma unroll
    for (int dt = 0; dt < 8; dt++)
#pragma unroll
      for (int r = 0; r < 4; r++) acc_o[dt][r] *= al[r];

    // P: C-layout -> LDS (wave-private slice, padded stride 72)
#pragma unroll
    for (int nt = 0; nt < 4; nt++)
#pragma unroll
      for (int r = 0; r < 4; r++)
        Ps[wave * 1152 + (quad * 4 + r) * 72 + nt * 16 + l16] = f2bf(s[nt][r]);
    __asm__ volatile("s_waitcnt lgkmcnt(0)" ::: "memory");

    // O += P V  (A-operand: P[m=lane&15][k=quad*8+j])
#pragma unroll
    for (int kk = 0; kk < 2; kk++) {
      const short8 ap = *(const short8*)(Ps + wave * 1152 + l16 * 72 + kk * 32 + quad * 8);
#pragma unroll
      for (int dt = 0; dt < 8; dt++) {
        const int vo = ((kk * 4 + quad) ^ (l16 & 7)) * 8;
        const short8 bv = *(const short8*)(Vs + (dt * 16 + l16) * 64 + vo);
        acc_o[dt] = __builtin_amdgcn_mfma_f32_16x16x32_bf16(ap, bv, acc_o[dt], 0, 0, 0);
      }
    }
    __syncthreads();
  }

  // epilogue: Oh[b*1024+s][h*128+d]
  ushort* Og = Oh + ((size_t)b * 1024 + q0 + wave * 16) * 4096 + h * 128;
#pragma unroll
  for (int r = 0; r < 4; r++) {
    const float inv = 1.0f / l_i[r];
#pragma unroll
    for (int dt = 0; dt < 8; dt++)
      Og[(size_t)(quad * 4 + r) * 4096 + dt * 16 + l16] = f2bf(acc_o[dt][r] * inv);
  }
}

// ---------------------------------------------------------------------------
extern "C" void kernel_launch(void* const* d_in, const int* in_sizes, int n_in,
                              void* d_out, int out_size, void* d_ws, size_t ws_size,
                              hipStream_t stream) {
  (void)in_sizes; (void)n_in; (void)out_size; (void)ws_size;
  const float* query = (const float*)d_in[0];
  const float* key = (const float*)d_in[1];
  const float* value = (const float*)d_in[2];
  const float* mask = (const float*)d_in[3];
  const float* wq = (const float*)d_in[4];
  const float* wk = (const float*)d_in[5];
  const float* wv = (const float*)d_in[6];
  const float* wo = (const float*)d_in[7];
  const int* pos = (const int*)d_in[8];
  float* out = (float*)d_out;

  char* ws = (char*)d_ws;
  const size_t MB = 1024 * 1024;
  // Region plan (peak 104 MiB, sequential-stream reuse):
  ushort* wqT = (ushort*)(ws + 0 * MB);    // [0,32): wqT, later Ohb
  ushort* Ohb = (ushort*)(ws + 0 * MB);
  ushort* Qhb = (ushort*)(ws + 32 * MB);   // [32,64): Qhb, later woT
  ushort* woT = (ushort*)(ws + 32 * MB);
  ushort* wkvT = (ushort*)(ws + 64 * MB);  // [64,80): wkT+wvT contiguous [2048][4096]
  ushort* Khb = (ushort*)(ws + 80 * MB);   // [80,88)
  ushort* Vtb = (ushort*)(ws + 88 * MB);   // [88,96)
  ushort* mbf = (ushort*)(ws + 96 * MB);   // [96,104): bf16 mask

  dim3 blk(256);
  cvt_f32_bf16<<<dim3(4096), blk, 0, stream>>>(mask, mbf, 1048576);

  transpose_cvt<<<dim3(64, 64), blk, 0, stream>>>(wq, wqT, 4096);
  // Q projection (scale 1/sqrt(128) folded; RoPE is linear so it commutes)
  gemm_bt<1, true><<<dim3(32, 32), blk, 0, stream>>>(
      query, nullptr, nullptr, wqT, Qhb, nullptr, nullptr, 4096, 0.08838834764831845f);

  transpose_cvt<<<dim3(16, 64), blk, 0, stream>>>(wk, wkvT, 1024);
  transpose_cvt<<<dim3(16, 64), blk, 0, stream>>>(wv, wkvT + (size_t)1024 * 4096, 1024);
  // fused K+V projection (N=2048; V written transposed)
  gemm_bt<4, true><<<dim3(16, 32), blk, 0, stream>>>(
      key, value, nullptr, wkvT, Khb, Vtb, nullptr, 2048, 1.0f);

  rope_kernel<<<dim3(131072 + 32768), dim3(64), 0, stream>>>(Qhb, Khb, pos, 131072);

  attn_kernel<<<dim3(16, 32, 4), blk, 0, stream>>>(Qhb, Khb, Vtb, mbf, Ohb);

  transpose_cvt<<<dim3(64, 64), blk, 0, stream>>>(wo, woT, 4096);  // Qhb dead
  // output projection -> fp32 d_out
  gemm_bt<0, false><<<dim3(32, 32), blk, 0, stream>>>(
      nullptr, nullptr, Ohb, woT, nullptr, nullptr, out, 4096, 1.0f);
}

// Round 3
// 971.118 us; speedup vs baseline: 1.0757x; 1.0757x over previous
//
#include <hip/hip_runtime.h>

// GQA attention forward. Inputs/outputs FP32 (per reference); internal compute
// bf16 MFMA. BS=4 SEQ=1024 DM=4096 HQ=32 HKV=8 DK=DV=128.
// R3: query pre-converted to bf16 (Q-proj uses pure global_load_lds path);
// RoPE fused into Q-proj / K-proj GEMM epilogues via j-remap so (d, d+64)
// pairs live in one thread's accumulators. rope_kernel deleted.

using ushort = unsigned short;
typedef __attribute__((ext_vector_type(8))) short short8;   // 8 bf16 (4 VGPRs)
typedef __attribute__((ext_vector_type(4))) short short4v;  // 4 bf16
typedef __attribute__((ext_vector_type(4))) float f32x4;    // MFMA C/D

__device__ __forceinline__ ushort f2bf(float x) {  // RNE fp32->bf16
  unsigned int u = __float_as_uint(x);
  u += 0x7FFFu + ((u >> 16) & 1u);
  return (ushort)(u >> 16);
}
__device__ __forceinline__ float bf2f(ushort h) {
  return __uint_as_float(((unsigned int)h) << 16);
}

__device__ __forceinline__ void async_copy16(const void* g, void* l) {
  // LDS dest = wave-uniform base + lane*16 (pass uniform l).
  __builtin_amdgcn_global_load_lds((const __attribute__((address_space(1))) void*)g,
                                   (__attribute__((address_space(3))) void*)l, 16, 0, 0);
}

// ---------------------------------------------------------------------------
// fp32 -> bf16 elementwise, 4 elems/thread
// ---------------------------------------------------------------------------
__global__ __launch_bounds__(256)
void cvt_f32_bf16(const float* __restrict__ in, ushort* __restrict__ out, int n4) {
  const int i = blockIdx.x * 256 + threadIdx.x;
  if (i < n4) {
    const float4 f = ((const float4*)in)[i];
    short4v v;
    v[0] = (short)f2bf(f.x); v[1] = (short)f2bf(f.y);
    v[2] = (short)f2bf(f.z); v[3] = (short)f2bf(f.w);
    ((short4v*)out)[i] = v;
  }
}

// ---------------------------------------------------------------------------
// Weight transpose+convert: B fp32 [4096][N] -> Bt bf16 [N][4096]
// ---------------------------------------------------------------------------
__global__ __launch_bounds__(256)
void transpose_cvt(const float* __restrict__ B, ushort* __restrict__ Bt, int N) {
  __shared__ ushort t[64][72];  // +8 pad breaks bank conflicts
  const int n0 = blockIdx.x * 64, k0 = blockIdx.y * 64;
  const int tid = threadIdx.x;
  const int r = tid >> 3, c8 = (tid & 7) * 8;
#pragma unroll
  for (int p = 0; p < 2; p++) {
    const float* src = B + (size_t)(k0 + r + p * 32) * N + n0 + c8;
    const float4 f0 = *(const float4*)src;
    const float4 f1 = *(const float4*)(src + 4);
    ushort* d = &t[r + p * 32][c8];
    d[0] = f2bf(f0.x); d[1] = f2bf(f0.y); d[2] = f2bf(f0.z); d[3] = f2bf(f0.w);
    d[4] = f2bf(f1.x); d[5] = f2bf(f1.y); d[6] = f2bf(f1.z); d[7] = f2bf(f1.w);
  }
  __syncthreads();
#pragma unroll
  for (int p = 0; p < 2; p++) {
    const int n = r + p * 32;
    short8 o;
#pragma unroll
    for (int j = 0; j < 8; j++) o[j] = (short)t[c8 + j][n];
    *(short8*)(Bt + (size_t)(n0 + n) * 4096 + k0 + c8) = o;
  }
}

// ---------------------------------------------------------------------------
// GEMM C = A[4096x4096] * Bt[Nx4096]^T, bf16 MFMA, fp32 accum. K=4096.
// j-remap: wave's n-columns = wn2 + (j&1)*16 + (j>>1)*64 + l16 so acc[i][j]
// and acc[i][j+2] hold the RoPE pair (d, d+64) in-register.
// MODE 0: C fp32 row-major [M][N] (O-projection -> d_out)
// MODE 1: Q head-major bf16 [b][32][s][128], RoPE+scale fused
// MODE 4 (AF32): fused KV; n0<1024 -> K bf16 [b][8][s][128] with RoPE;
//                n0>=1024 -> V^T bf16 [b][8][128][s]
// ---------------------------------------------------------------------------
template <int MODE, bool AF32>
__global__ __launch_bounds__(256, 2)
void gemm_bt(const float* __restrict__ Af, const float* __restrict__ A2f,
             const ushort* __restrict__ Abf, const ushort* __restrict__ Bt,
             ushort* __restrict__ C, ushort* __restrict__ C2,
             float* __restrict__ Cf, const int* __restrict__ posp,
             int N, float scale) {
  constexpr int K = 4096;
  __shared__ alignas(16) ushort As[128 * 32];
  __shared__ alignas(16) ushort Bs[128 * 32];
  const int tid = threadIdx.x;
  const int wave = tid >> 6, lane = tid & 63;
  const int quad = lane >> 4, l16 = lane & 15;
  const int m0 = blockIdx.y * 128, n0 = blockIdx.x * 128;
  const int wm = (wave & 1) * 64, wn2 = (wave >> 1) * 32;

  const size_t aoff = (size_t)(m0 + wave * 16 + (lane >> 2)) * K + (lane & 3) * 8;
  const float* gAf = nullptr;
  const ushort* gAb = nullptr;
  if constexpr (AF32) {
    const float* Ause = Af;
    if constexpr (MODE == 4) {
      if (n0 >= 1024) Ause = A2f;  // V half reads `value`
    }
    gAf = Ause + aoff;
  } else {
    gAb = Abf + aoff;
  }
  const ushort* gB = Bt + (size_t)(n0 + wave * 16 + (lane >> 2)) * K + (lane & 3) * 8;
  ushort* lA = As + wave * 512;  // wave-uniform LDS bases
  ushort* lB = Bs + wave * 512;
  constexpr size_t rstep = (size_t)64 * K;

  f32x4 acc[4][4] = {};

  for (int kt = 0; kt < K; kt += 32) {
    if constexpr (AF32) {
      const float4 a0 = *(const float4*)(gAf + kt);
      const float4 a1 = *(const float4*)(gAf + kt + 4);
      const float4 b0 = *(const float4*)(gAf + rstep + kt);
      const float4 b1 = *(const float4*)(gAf + rstep + kt + 4);
      short8 v0, v1;
      v0[0] = (short)f2bf(a0.x); v0[1] = (short)f2bf(a0.y);
      v0[2] = (short)f2bf(a0.z); v0[3] = (short)f2bf(a0.w);
      v0[4] = (short)f2bf(a1.x); v0[5] = (short)f2bf(a1.y);
      v0[6] = (short)f2bf(a1.z); v0[7] = (short)f2bf(a1.w);
      v1[0] = (short)f2bf(b0.x); v1[1] = (short)f2bf(b0.y);
      v1[2] = (short)f2bf(b0.z); v1[3] = (short)f2bf(b0.w);
      v1[4] = (short)f2bf(b1.x); v1[5] = (short)f2bf(b1.y);
      v1[6] = (short)f2bf(b1.z); v1[7] = (short)f2bf(b1.w);
      *(short8*)(lA + lane * 8) = v0;
      *(short8*)(lA + 2048 + lane * 8) = v1;
    } else {
      async_copy16(gAb + kt, lA);
      async_copy16(gAb + rstep + kt, lA + 2048);
    }
    async_copy16(gB + kt, lB);
    async_copy16(gB + rstep + kt, lB + 2048);
    __syncthreads();
    short8 af[4], bfrag[4];
#pragma unroll
    for (int i = 0; i < 4; i++) {
      af[i] = *(const short8*)(As + (wm + i * 16 + l16) * 32 + quad * 8);
      bfrag[i] = *(const short8*)(
          Bs + (wn2 + (i & 1) * 16 + (i >> 1) * 64 + l16) * 32 + quad * 8);
    }
#pragma unroll
    for (int i = 0; i < 4; i++)
#pragma unroll
      for (int j = 0; j < 4; j++)
        acc[i][j] = __builtin_amdgcn_mfma_f32_16x16x32_bf16(af[i], bfrag[j],
                                                            acc[i][j], 0, 0, 0);
    __syncthreads();
  }

  // ---------------- epilogue ----------------
  if constexpr (MODE == 0) {
#pragma unroll
    for (int i = 0; i < 4; i++)
#pragma unroll
      for (int j = 0; j < 4; j++) {
        const int n = n0 + wn2 + (j & 1) * 16 + (j >> 1) * 64 + l16;
        const int mb = m0 + wm + i * 16 + quad * 4;
#pragma unroll
        for (int r = 0; r < 4; r++)
          Cf[(size_t)(mb + r) * N + n] = acc[i][j][r] * scale;
      }
  } else {
    const bool kv_v = (MODE == 4) && (n0 >= 1024);
    if (!kv_v) {
      // RoPE epilogue (Q: MODE 1, K: MODE 4 low half)
      const int pos0 = posp[0];
      const int h = (MODE == 1) ? (n0 >> 7) : (n0 >> 7);
      const int NH = (MODE == 1) ? 32 : 8;
      constexpr float lgbase = -0.20762050593045983f;  // -log2(10000)/64
      float invf[2];
      invf[0] = exp2f((float)(wn2 + l16) * lgbase);
      invf[1] = exp2f((float)(wn2 + 16 + l16) * lgbase);
#pragma unroll
      for (int i = 0; i < 4; i++) {
#pragma unroll
        for (int r = 0; r < 4; r++) {
          const int m = m0 + wm + i * 16 + quad * 4 + r;
          const int s = m & 1023, bb = m >> 10;
          const float p = (float)(s + pos0);
          ushort* row = C + (((size_t)bb * NH + h) * 1024 + s) * 128;
#pragma unroll
          for (int jj = 0; jj < 2; jj++) {
            float sn, cs;
            sincosf(p * invf[jj], &sn, &cs);
            const float x1 = acc[i][jj][r] * scale;
            const float x2 = acc[i][jj + 2][r] * scale;
            const int dlo = wn2 + jj * 16 + l16;
            row[dlo] = f2bf(x1 * cs - x2 * sn);
            row[dlo + 64] = f2bf(x2 * cs + x1 * sn);
          }
        }
      }
    } else {
      // V half: no RoPE, transposed write [b][8][128][s]
      const int hh = (n0 - 1024) >> 7;
#pragma unroll
      for (int i = 0; i < 4; i++)
#pragma unroll
        for (int j = 0; j < 4; j++) {
          const int d = wn2 + (j & 1) * 16 + (j >> 1) * 64 + l16;
          const int mb = m0 + wm + i * 16 + quad * 4;
#pragma unroll
          for (int r = 0; r < 4; r++) {
            const int m = mb + r;
            const int bb = m >> 10, s = m & 1023;
            C2[(((size_t)bb * 8 + hh) * 128 + d) * 1024 + s] = f2bf(acc[i][j][r]);
          }
        }
    }
  }
}

// ---------------------------------------------------------------------------
// Flash attention. Block = 64 q-rows (4 waves x 16), 16 k-tiles of 64.
// XOR-swizzled 16B chunks for K/V/Q staging (conflict-free ds_read_b128).
// P staging aliases Ks (guarded by mid-iteration barrier). LDS = 56 KB.
// ---------------------------------------------------------------------------
__global__ __launch_bounds__(256, 2)
void attn_kernel(const ushort* __restrict__ Qh, const ushort* __restrict__ Kh,
                 const ushort* __restrict__ Vt, const ushort* __restrict__ Mk,
                 ushort* __restrict__ Oh) {
  __shared__ alignas(16) ushort Qs[64 * 128];
  __shared__ alignas(16) ushort Ks[64 * 128];
  __shared__ alignas(16) ushort Vs[128 * 64];  // [d][key]
  __shared__ alignas(16) ushort Ms[64 * 64];   // bf16 mask tile
  ushort* Ps = Ks;  // alias, guarded by mid-barrier
  const int b = blockIdx.z, h = blockIdx.y;
  const int q0 = blockIdx.x * 64;
  const int hkv = h >> 2;
  const int tid = threadIdx.x;
  const int wave = tid >> 6, lane = tid & 63;
  const int quad = lane >> 4, l16 = lane & 15;

  const ushort* Qg = Qh + (((size_t)b * 32 + h) * 1024 + q0) * 128;
  const ushort* Kg = Kh + ((size_t)b * 8 + hkv) * (size_t)(1024 * 128);
  const ushort* Vg = Vt + ((size_t)b * 8 + hkv) * (size_t)(128 * 1024);
  const ushort* Mg = Mk + ((size_t)b * 1024 + q0) * 1024;

#pragma unroll
  for (int c = 0; c < 4; c++) {  // stage Q once, swizzled
    const int i = wave * 4 + c;
    const int row = i * 4 + (lane >> 4);
    const int kc = (lane & 15) ^ (c * 4 + (lane >> 4));
    async_copy16(Qg + (size_t)row * 128 + kc * 8, Qs + i * 512);
  }

  float m_i[4], l_i[4];
#pragma unroll
  for (int r = 0; r < 4; r++) { m_i[r] = -1e30f; l_i[r] = 0.0f; }
  f32x4 acc_o[8] = {};

  const int vr = lane >> 3;
  const int vkc = (lane & 7) ^ (vr & 7);

  for (int kt = 0; kt < 1024; kt += 64) {
#pragma unroll
    for (int c = 0; c < 4; c++) {  // K tile 64x128, swizzled
      const int i = wave * 4 + c;
      const int row = i * 4 + (lane >> 4);
      const int kc = (lane & 15) ^ (c * 4 + (lane >> 4));
      async_copy16(Kg + (size_t)(kt + row) * 128 + kc * 8, Ks + i * 512);
    }
#pragma unroll
    for (int c = 0; c < 4; c++) {  // V^T tile 128x64, 8-chunk swizzle
      const int i = wave * 4 + c;
      async_copy16(Vg + (size_t)(i * 8 + vr) * 1024 + kt + vkc * 8, Vs + i * 512);
    }
#pragma unroll
    for (int c = 0; c < 2; c++)  // mask tile 64x64 bf16, linear
      async_copy16(Mg + (size_t)(wave * 8 + c * 32 + vr) * 1024 + kt + (lane & 7) * 8,
                   Ms + wave * 512 + c * 2048);
    __syncthreads();

    // S = Q K^T (Q pre-scaled by 1/sqrt(128))
    f32x4 s[4] = {};
    const int qrow = (wave * 16 + l16) * 128;
#pragma unroll
    for (int ks = 0; ks < 4; ks++) {
      const int ko = ((ks * 4 + quad) ^ l16) * 8;
      const short8 aq = *(const short8*)(Qs + qrow + ko);
#pragma unroll
      for (int nt = 0; nt < 4; nt++) {
        const short8 bk = *(const short8*)(Ks + (nt * 16 + l16) * 128 + ko);
        s[nt] = __builtin_amdgcn_mfma_f32_16x16x32_bf16(aq, bk, s[nt], 0, 0, 0);
      }
    }
    __syncthreads();  // Ks reads done before P overwrites Ks region

    // additive mask (C/D layout: row = quad*4+reg, col = lane&15)
#pragma unroll
    for (int nt = 0; nt < 4; nt++)
#pragma unroll
      for (int r = 0; r < 4; r++)
        s[nt][r] += bf2f(Ms[(wave * 16 + quad * 4 + r) * 64 + nt * 16 + l16]);

    // online softmax: quad's 16 lanes hold one row's 16 columns
    float al[4];
#pragma unroll
    for (int r = 0; r < 4; r++) {
      float mx = fmaxf(fmaxf(s[0][r], s[1][r]), fmaxf(s[2][r], s[3][r]));
#pragma unroll
      for (int off = 1; off < 16; off <<= 1) mx = fmaxf(mx, __shfl_xor(mx, off));
      const float mnew = fmaxf(m_i[r], mx);
      al[r] = __expf(m_i[r] - mnew);
      float sum = 0.0f;
#pragma unroll
      for (int nt = 0; nt < 4; nt++) {
        const float pv = __expf(s[nt][r] - mnew);
        s[nt][r] = pv;
        sum += pv;
      }
#pragma unroll
      for (int off = 1; off < 16; off <<= 1) sum += __shfl_xor(sum, off);
      l_i[r] = l_i[r] * al[r] + sum;
      m_i[r] = mnew;
    }
#pragma unroll
    for (int dt = 0; dt < 8; dt++)
#pragma unroll
      for (int r = 0; r < 4; r++) acc_o[dt][r] *= al[r];

    // P: C-layout -> LDS (wave-private slice, padded stride 72)
#pragma unroll
    for (int nt = 0; nt < 4; nt++)
#pragma unroll
      for (int r = 0; r < 4; r++)
        Ps[wave * 1152 + (quad * 4 + r) * 72 + nt * 16 + l16] = f2bf(s[nt][r]);
    __asm__ volatile("s_waitcnt lgkmcnt(0)" ::: "memory");

    // O += P V  (A-operand: P[m=lane&15][k=quad*8+j])
#pragma unroll
    for (int kk = 0; kk < 2; kk++) {
      const short8 ap = *(const short8*)(Ps + wave * 1152 + l16 * 72 + kk * 32 + quad * 8);
#pragma unroll
      for (int dt = 0; dt < 8; dt++) {
        const int vo = ((kk * 4 + quad) ^ (l16 & 7)) * 8;
        const short8 bv = *(const short8*)(Vs + (dt * 16 + l16) * 64 + vo);
        acc_o[dt] = __builtin_amdgcn_mfma_f32_16x16x32_bf16(ap, bv, acc_o[dt], 0, 0, 0);
      }
    }
    __syncthreads();
  }

  // epilogue: Oh[b*1024+s][h*128+d]
  ushort* Og = Oh + ((size_t)b * 1024 + q0 + wave * 16) * 4096 + h * 128;
#pragma unroll
  for (int r = 0; r < 4; r++) {
    const float inv = 1.0f / l_i[r];
#pragma unroll
    for (int dt = 0; dt < 8; dt++)
      Og[(size_t)(quad * 4 + r) * 4096 + dt * 16 + l16] = f2bf(acc_o[dt][r] * inv);
  }
}

// ---------------------------------------------------------------------------
extern "C" void kernel_launch(void* const* d_in, const int* in_sizes, int n_in,
                              void* d_out, int out_size, void* d_ws, size_t ws_size,
                              hipStream_t stream) {
  (void)in_sizes; (void)n_in; (void)out_size; (void)ws_size;
  const float* query = (const float*)d_in[0];
  const float* key = (const float*)d_in[1];
  const float* value = (const float*)d_in[2];
  const float* mask = (const float*)d_in[3];
  const float* wq = (const float*)d_in[4];
  const float* wk = (const float*)d_in[5];
  const float* wv = (const float*)d_in[6];
  const float* wo = (const float*)d_in[7];
  const int* pos = (const int*)d_in[8];
  float* out = (float*)d_out;

  char* ws = (char*)d_ws;
  const size_t MB = 1024 * 1024;
  // Region reuse plan (peak 104 MiB):
  ushort* qb = (ushort*)(ws + 0 * MB);     // [0,32): qb -> Khb[0,8)+Vtb[8,16)
  ushort* Khb = (ushort*)(ws + 0 * MB);
  ushort* Vtb = (ushort*)(ws + 8 * MB);
  ushort* wqT = (ushort*)(ws + 32 * MB);   // [32,64): wqT -> wkvT[32,48) -> Ohb[32,64)
  ushort* wkvT = (ushort*)(ws + 32 * MB);
  ushort* Ohb = (ushort*)(ws + 32 * MB);
  ushort* Qhb = (ushort*)(ws + 64 * MB);   // [64,96): Qhb -> woT
  ushort* woT = (ushort*)(ws + 64 * MB);
  ushort* mbf = (ushort*)(ws + 96 * MB);   // [96,104)

  dim3 blk(256);
  cvt_f32_bf16<<<dim3(4096), blk, 0, stream>>>(mask, mbf, 1048576);
  cvt_f32_bf16<<<dim3(16384), blk, 0, stream>>>(query, qb, 4194304);

  transpose_cvt<<<dim3(64, 64), blk, 0, stream>>>(wq, wqT, 4096);
  // Q projection, scale + RoPE fused
  gemm_bt<1, false><<<dim3(32, 32), blk, 0, stream>>>(
      nullptr, nullptr, qb, wqT, Qhb, nullptr, nullptr, pos, 4096,
      0.08838834764831845f);

  transpose_cvt<<<dim3(16, 64), blk, 0, stream>>>(wk, wkvT, 1024);
  transpose_cvt<<<dim3(16, 64), blk, 0, stream>>>(wv, wkvT + (size_t)1024 * 4096, 1024);
  // fused K+V projection (K gets RoPE; V written transposed)
  gemm_bt<4, true><<<dim3(16, 32), blk, 0, stream>>>(
      key, value, nullptr, wkvT, Khb, Vtb, nullptr, pos, 2048, 1.0f);

  attn_kernel<<<dim3(16, 32, 4), blk, 0, stream>>>(Qhb, Khb, Vtb, mbf, Ohb);

  transpose_cvt<<<dim3(64, 64), blk, 0, stream>>>(wo, woT, 4096);  // Qhb dead
  // output projection -> fp32 d_out
  gemm_bt<0, false><<<dim3(32, 32), blk, 0, stream>>>(
      nullptr, nullptr, Ohb, woT, nullptr, nullptr, out, pos, 4096, 1.0f);
}